// Round 1
// baseline (3117.450 us; speedup 1.0000x reference)
//
#include <hip/hip_runtime.h>
#include <math.h>

#define N_NODES 50000
#define N_EDGES 400000
#define DH 128
#define DO 64
#define E_IN 208   // 64 + 64 + 64 + 16
#define N_IN 144   // 64 + 64 + 16

// ---------------------------------------------------------------------------
// Shared MLP layer: sDst[e][0:OW] = (relu?)(sSrc[e][0:K] @ W + b)
// Thread mapping: f = tid&127 (output feature), half = tid>>7 (edge half).
// Each thread computes 16 edges for one output feature.
// LDS reads are wave-broadcast (all lanes of a half read same addr) -> no
// bank conflicts; weight loads are coalesced (lanes span consecutive f).
// ---------------------------------------------------------------------------
template<int K, int OW, bool RELU>
__device__ __forceinline__ void mlp_layer(const float* __restrict__ W,
                                          const float* __restrict__ bias,
                                          const float* sSrc, float* sDst,
                                          int f, int half) {
  if (OW == DO && f >= DO) return;   // final layer is 64 wide
  float acc[16];
#pragma unroll
  for (int e = 0; e < 16; ++e) acc[e] = 0.f;
  const float* s0 = sSrc + half * 16 * K;
  for (int k = 0; k < K; k += 4) {
    float w0 = W[(k + 0) * OW + f];
    float w1 = W[(k + 1) * OW + f];
    float w2 = W[(k + 2) * OW + f];
    float w3 = W[(k + 3) * OW + f];
#pragma unroll
    for (int e = 0; e < 16; ++e) {
      float4 h = *(const float4*)(s0 + e * K + k);
      acc[e] = fmaf(h.w, w3, fmaf(h.z, w2, fmaf(h.y, w1, fmaf(h.x, w0, acc[e]))));
    }
  }
  float bf = bias[f];
#pragma unroll
  for (int e = 0; e < 16; ++e) {
    float v = acc[e] + bf;
    if (RELU) v = fmaxf(v, 0.f);
    sDst[(half * 16 + e) * OW + f] = v;
  }
}

struct EdgeParams {
  const float *x, *edge_attr, *u;
  const int *edge_index, *batch;
  const float *eWin, *eBin, *eWh, *eBh, *eWout, *eBout, *eG, *eBt;
  const float *aWin, *aBin, *aWh, *aBh, *aWout, *aBout, *aG, *aBt;
  float* agg;
};

// 32 edges per block. LDS budget (58KB, 2 blocks/CU):
//   sIn [32*208]  staging; after layer-1 reused as: B = sIn[0..4096),
//                 preE = sIn[4096..6144)
//   sAe [32*128]  e-MLP ping buffer; reused as preA after e-MLP done
//   sAa [32*128]  a-MLP ping buffer
__global__ __launch_bounds__(256, 2) void edge_kernel(EdgeParams p) {
  __shared__ __align__(16) float sIn[32 * E_IN];
  __shared__ __align__(16) float sAe[32 * DH];
  __shared__ __align__(16) float sAa[32 * DH];
  __shared__ int sSrc[32], sTgt[32];

  const int tid = threadIdx.x;
  const int e0 = blockIdx.x * 32;

  if (tid < 32) {
    sSrc[tid] = p.edge_index[e0 + tid];
    sTgt[tid] = p.edge_index[N_EDGES + e0 + tid];
  }
  __syncthreads();

  // Stage neigh = [x[src] | x[tgt] | edge_attr | u[batch[src]]]  (float4 granular)
  for (int idx = tid; idx < 32 * 52; idx += 256) {
    int e = idx / 52, c4 = idx % 52;
    float4 v;
    if (c4 < 16)      v = *(const float4*)(p.x + (size_t)sSrc[e] * 64 + c4 * 4);
    else if (c4 < 32) v = *(const float4*)(p.x + (size_t)sTgt[e] * 64 + (c4 - 16) * 4);
    else if (c4 < 48) v = *(const float4*)(p.edge_attr + (size_t)(e0 + e) * 64 + (c4 - 32) * 4);
    else {
      int eb = p.batch[sSrc[e]];
      v = *(const float4*)(p.u + eb * 16 + (c4 - 48) * 4);
    }
    *(float4*)(sIn + e * E_IN + c4 * 4) = v;
  }
  __syncthreads();

  const int f = tid & 127, half = tid >> 7;
  float* B    = sIn;             // 32*128 floats
  float* preE = sIn + 32 * DH;   // 32*64 floats
  float* preA = sAe;

  // layer 1 for both MLPs while sIn is live
  mlp_layer<E_IN, DH, true>(p.eWin, p.eBin, sIn, sAe, f, half);
  mlp_layer<E_IN, DH, true>(p.aWin, p.aBin, sIn, sAa, f, half);
  __syncthreads();
  // e-MLP
  mlp_layer<DH, DH, true>(p.eWh,           p.eBh,      sAe, B,    f, half); __syncthreads();
  mlp_layer<DH, DH, true>(p.eWh + DH * DH, p.eBh + DH, B,   sAe,  f, half); __syncthreads();
  mlp_layer<DH, DO, false>(p.eWout,        p.eBout,    sAe, preE, f, half); __syncthreads();
  // a-MLP
  mlp_layer<DH, DH, true>(p.aWh,           p.aBh,      sAa, B,    f, half); __syncthreads();
  mlp_layer<DH, DH, true>(p.aWh + DH * DH, p.aBh + DH, B,   sAa,  f, half); __syncthreads();
  mlp_layer<DH, DO, false>(p.aWout,        p.aBout,    sAa, preA, f, half); __syncthreads();

  // LayerNorm(e), LayerNorm(a) -> sigmoid -> multiply -> atomic scatter to agg[tgt]
  const int e = tid >> 3, j = tid & 7;   // 8 threads per edge, 8 feats each
  float ve[8], va[8];
  float s1e = 0.f, s2e = 0.f, s1a = 0.f, s2a = 0.f;
#pragma unroll
  for (int i = 0; i < 8; ++i) {
    float a_ = preE[e * 64 + j * 8 + i]; ve[i] = a_; s1e += a_; s2e += a_ * a_;
    float b_ = preA[e * 64 + j * 8 + i]; va[i] = b_; s1a += b_; s2a += b_ * b_;
  }
#pragma unroll
  for (int d = 1; d < 8; d <<= 1) {
    s1e += __shfl_xor(s1e, d); s2e += __shfl_xor(s2e, d);
    s1a += __shfl_xor(s1a, d); s2a += __shfl_xor(s2a, d);
  }
  float mue = s1e * (1.f / 64), mua = s1a * (1.f / 64);
  float rse = rsqrtf(s2e * (1.f / 64) - mue * mue + 1e-5f);
  float rsa = rsqrtf(s2a * (1.f / 64) - mua * mua + 1e-5f);
  int t = sTgt[e];
#pragma unroll
  for (int i = 0; i < 8; ++i) {
    int fc = j * 8 + i;
    float oe = (ve[i] - mue) * rse * p.eG[fc] + p.eBt[fc];
    float oa = (va[i] - mua) * rsa * p.aG[fc] + p.aBt[fc];
    float o = oe / (1.f + expf(-oa));
    atomicAdd(p.agg + (size_t)t * 64 + fc, o);
  }
}

struct NodeParams {
  const float *x, *u;
  const int *batch;
  const float *Win, *Bin, *Wh, *Bh, *Wout, *Bout, *G, *Bt;
  const float *agg;
  float* out;
};

// 32 nodes per block. LDS: sIn[32*144] (reused as pre after layer 1),
// sA/sB [32*128] ping-pong. ~51KB -> 2 blocks/CU.
__global__ __launch_bounds__(256, 2) void node_kernel(NodeParams p) {
  __shared__ __align__(16) float sIn[32 * N_IN];
  __shared__ __align__(16) float sA[32 * DH];
  __shared__ __align__(16) float sB[32 * DH];

  const int tid = threadIdx.x;
  const int n0 = blockIdx.x * 32;

  for (int idx = tid; idx < 32 * 36; idx += 256) {
    int r = idx / 36, c4 = idx % 36;
    int n = n0 + r;
    float4 v = make_float4(0.f, 0.f, 0.f, 0.f);
    if (n < N_NODES) {
      if (c4 < 16)      v = *(const float4*)(p.x + (size_t)n * 64 + c4 * 4);
      else if (c4 < 32) v = *(const float4*)(p.agg + (size_t)n * 64 + (c4 - 16) * 4);
      else              v = *(const float4*)(p.u + p.batch[n] * 16 + (c4 - 32) * 4);
    }
    *(float4*)(sIn + r * N_IN + c4 * 4) = v;
  }
  __syncthreads();

  const int f = tid & 127, half = tid >> 7;
  mlp_layer<N_IN, DH, true>(p.Win, p.Bin, sIn, sA, f, half); __syncthreads();
  mlp_layer<DH, DH, true>(p.Wh,           p.Bh,      sA, sB, f, half); __syncthreads();
  mlp_layer<DH, DH, true>(p.Wh + DH * DH, p.Bh + DH, sB, sA, f, half); __syncthreads();
  float* pre = sIn;  // sIn dead after layer 1
  mlp_layer<DH, DO, false>(p.Wout, p.Bout, sA, pre, f, half); __syncthreads();

  const int e = tid >> 3, j = tid & 7;
  const int n = n0 + e;
  float vv[8];
  float s1 = 0.f, s2 = 0.f;
#pragma unroll
  for (int i = 0; i < 8; ++i) {
    float a_ = pre[e * 64 + j * 8 + i]; vv[i] = a_; s1 += a_; s2 += a_ * a_;
  }
#pragma unroll
  for (int d = 1; d < 8; d <<= 1) {
    s1 += __shfl_xor(s1, d); s2 += __shfl_xor(s2, d);
  }
  float mu = s1 * (1.f / 64);
  float rs = rsqrtf(s2 * (1.f / 64) - mu * mu + 1e-5f);
  if (n < N_NODES) {
#pragma unroll
    for (int i = 0; i < 8; ++i) {
      int fc = j * 8 + i;
      p.out[(size_t)n * 64 + fc] = (vv[i] - mu) * rs * p.G[fc] + p.Bt[fc];
    }
  }
}

extern "C" void kernel_launch(void* const* d_in, const int* in_sizes, int n_in,
                              void* d_out, int out_size, void* d_ws, size_t ws_size,
                              hipStream_t stream) {
  const float* x         = (const float*)d_in[0];
  const float* edge_attr = (const float*)d_in[1];
  const float* u         = (const float*)d_in[2];
  const int*   edge_index= (const int*)d_in[3];
  const int*   batch     = (const int*)d_in[4];

  float* agg = (float*)d_ws;  // [N_NODES, 64]
  hipMemsetAsync(agg, 0, (size_t)N_NODES * 64 * sizeof(float), stream);

  EdgeParams ep;
  ep.x = x; ep.edge_attr = edge_attr; ep.u = u;
  ep.edge_index = edge_index; ep.batch = batch;
  ep.eWin = (const float*)d_in[5];  ep.eBin  = (const float*)d_in[6];
  ep.eWh  = (const float*)d_in[7];  ep.eBh   = (const float*)d_in[8];
  ep.eWout= (const float*)d_in[9];  ep.eBout = (const float*)d_in[10];
  ep.eG   = (const float*)d_in[11]; ep.eBt   = (const float*)d_in[12];
  ep.aWin = (const float*)d_in[13]; ep.aBin  = (const float*)d_in[14];
  ep.aWh  = (const float*)d_in[15]; ep.aBh   = (const float*)d_in[16];
  ep.aWout= (const float*)d_in[17]; ep.aBout = (const float*)d_in[18];
  ep.aG   = (const float*)d_in[19]; ep.aBt   = (const float*)d_in[20];
  ep.agg  = agg;
  edge_kernel<<<N_EDGES / 32, 256, 0, stream>>>(ep);

  NodeParams np;
  np.x = x; np.u = u; np.batch = batch;
  np.Win  = (const float*)d_in[21]; np.Bin  = (const float*)d_in[22];
  np.Wh   = (const float*)d_in[23]; np.Bh   = (const float*)d_in[24];
  np.Wout = (const float*)d_in[25]; np.Bout = (const float*)d_in[26];
  np.G    = (const float*)d_in[27]; np.Bt   = (const float*)d_in[28];
  np.agg  = agg;
  np.out  = (float*)d_out;
  node_kernel<<<(N_NODES + 31) / 32, 256, 0, stream>>>(np);
}

// Round 2
// 594.437 us; speedup vs baseline: 5.2444x; 5.2444x over previous
//
#include <hip/hip_runtime.h>
#include <math.h>

#define N_NODES 50000
#define N_EDGES 400000

typedef _Float16 half8 __attribute__((ext_vector_type(8)));
typedef float f32x4 __attribute__((ext_vector_type(4)));

#define LD1 232   // edge L1 input ld (K=208 padded to 224, +8 bank pad)
#define LDH 136   // hidden activation ld (128 + 8 pad)
#define LDN 168   // node L1 input ld (K=144 padded to 160, +8 pad)

// workspace layout (bytes)
#define AGG_OFF 0           // 50000*64 f32 = 12.8 MB
#define XH_OFF  12800000    // 50000*64 f16
#define UH_OFF  19200000    // 64*16 f16
#define WP_OFF  19202048    // packed weights, 200704 f16
// packed-weight offsets (f16 elements)
#define O_EW1 0
#define O_EH0 28672
#define O_EH1 45056
#define O_EWO 61440
#define O_AW1 69632
#define O_AH0 98304
#define O_AH1 114688
#define O_AWO 131072
#define O_NW1 139264
#define O_NH0 159744
#define O_NH1 176128
#define O_NWO 192512

__device__ __forceinline__ f32x4 mfma16(half8 a, half8 b, f32x4 c) {
  return __builtin_amdgcn_mfma_f32_16x16x32_f16(a, b, c, 0, 0, 0);
}

// ---------------------------------------------------------------------------
// Hidden layer: 64 rows x K=128 -> N=128, wave w owns cols [w*32, w*32+32).
// A from LDS (ld=LDH), B from packed global (L2-resident), relu, f16 out.
// ---------------------------------------------------------------------------
__device__ __forceinline__ void gemm_h(const _Float16* __restrict__ src,
                                       _Float16* __restrict__ dst,
                                       const _Float16* __restrict__ wp16,
                                       const float* __restrict__ bias,
                                       int w, int lane) {
  const half8* wp = (const half8*)wp16;
  const int r = lane & 15, ch = lane >> 4;
  f32x4 a0[4], a1[4];
#pragma unroll
  for (int m = 0; m < 4; ++m) {
    a0[m] = (f32x4){0.f, 0.f, 0.f, 0.f};
    a1[m] = (f32x4){0.f, 0.f, 0.f, 0.f};
  }
#pragma unroll
  for (int s = 0; s < 4; ++s) {
    half8 b0 = wp[(s * 4 + ch) * 128 + w * 32 + r];
    half8 b1 = wp[(s * 4 + ch) * 128 + w * 32 + 16 + r];
#pragma unroll
    for (int m = 0; m < 4; ++m) {
      half8 a = *(const half8*)(src + (m * 16 + r) * LDH + s * 32 + ch * 8);
      a0[m] = mfma16(a, b0, a0[m]);
      a1[m] = mfma16(a, b1, a1[m]);
    }
  }
  float bb0 = bias[w * 32 + r], bb1 = bias[w * 32 + 16 + r];
#pragma unroll
  for (int m = 0; m < 4; ++m)
#pragma unroll
    for (int q = 0; q < 4; ++q) {
      int row = m * 16 + ch * 4 + q;
      dst[row * LDH + w * 32 + r]      = (_Float16)fmaxf(a0[m][q] + bb0, 0.f);
      dst[row * LDH + w * 32 + 16 + r] = (_Float16)fmaxf(a1[m][q] + bb1, 0.f);
    }
}

// Edge layer-1: K=224 (padded), both e- and a-MLP share A-fragments.
__device__ __forceinline__ void gemm_l1_dual(const _Float16* __restrict__ sIn,
                                             _Float16* __restrict__ dQ,
                                             _Float16* __restrict__ dR,
                                             const _Float16* wpE16, const _Float16* wpA16,
                                             const float* __restrict__ bE,
                                             const float* __restrict__ bA,
                                             int w, int lane) {
  const half8* wpE = (const half8*)wpE16;
  const half8* wpA = (const half8*)wpA16;
  const int r = lane & 15, ch = lane >> 4;
  f32x4 e0[4], e1[4], q0[4], q1[4];
#pragma unroll
  for (int m = 0; m < 4; ++m) {
    e0[m] = (f32x4){0.f, 0.f, 0.f, 0.f}; e1[m] = (f32x4){0.f, 0.f, 0.f, 0.f};
    q0[m] = (f32x4){0.f, 0.f, 0.f, 0.f}; q1[m] = (f32x4){0.f, 0.f, 0.f, 0.f};
  }
#pragma unroll
  for (int s = 0; s < 7; ++s) {
    half8 be0 = wpE[(s * 4 + ch) * 128 + w * 32 + r];
    half8 be1 = wpE[(s * 4 + ch) * 128 + w * 32 + 16 + r];
    half8 ba0 = wpA[(s * 4 + ch) * 128 + w * 32 + r];
    half8 ba1 = wpA[(s * 4 + ch) * 128 + w * 32 + 16 + r];
#pragma unroll
    for (int m = 0; m < 4; ++m) {
      half8 a = *(const half8*)(sIn + (m * 16 + r) * LD1 + s * 32 + ch * 8);
      e0[m] = mfma16(a, be0, e0[m]);
      e1[m] = mfma16(a, be1, e1[m]);
      q0[m] = mfma16(a, ba0, q0[m]);
      q1[m] = mfma16(a, ba1, q1[m]);
    }
  }
  float be0v = bE[w * 32 + r], be1v = bE[w * 32 + 16 + r];
  float ba0v = bA[w * 32 + r], ba1v = bA[w * 32 + 16 + r];
#pragma unroll
  for (int m = 0; m < 4; ++m)
#pragma unroll
    for (int q = 0; q < 4; ++q) {
      int row = m * 16 + ch * 4 + q;
      dQ[row * LDH + w * 32 + r]      = (_Float16)fmaxf(e0[m][q] + be0v, 0.f);
      dQ[row * LDH + w * 32 + 16 + r] = (_Float16)fmaxf(e1[m][q] + be1v, 0.f);
      dR[row * LDH + w * 32 + r]      = (_Float16)fmaxf(q0[m][q] + ba0v, 0.f);
      dR[row * LDH + w * 32 + 16 + r] = (_Float16)fmaxf(q1[m][q] + ba1v, 0.f);
    }
}

// Node layer-1: K=160 (padded), single MLP.
__device__ __forceinline__ void gemm_l1n(const _Float16* __restrict__ sIn,
                                         _Float16* __restrict__ dst,
                                         const _Float16* wp16,
                                         const float* __restrict__ bias,
                                         int w, int lane) {
  const half8* wp = (const half8*)wp16;
  const int r = lane & 15, ch = lane >> 4;
  f32x4 a0[4], a1[4];
#pragma unroll
  for (int m = 0; m < 4; ++m) {
    a0[m] = (f32x4){0.f, 0.f, 0.f, 0.f};
    a1[m] = (f32x4){0.f, 0.f, 0.f, 0.f};
  }
#pragma unroll
  for (int s = 0; s < 5; ++s) {
    half8 b0 = wp[(s * 4 + ch) * 128 + w * 32 + r];
    half8 b1 = wp[(s * 4 + ch) * 128 + w * 32 + 16 + r];
#pragma unroll
    for (int m = 0; m < 4; ++m) {
      half8 a = *(const half8*)(sIn + (m * 16 + r) * LDN + s * 32 + ch * 8);
      a0[m] = mfma16(a, b0, a0[m]);
      a1[m] = mfma16(a, b1, a1[m]);
    }
  }
  float bb0 = bias[w * 32 + r], bb1 = bias[w * 32 + 16 + r];
#pragma unroll
  for (int m = 0; m < 4; ++m)
#pragma unroll
    for (int q = 0; q < 4; ++q) {
      int row = m * 16 + ch * 4 + q;
      dst[row * LDH + w * 32 + r]      = (_Float16)fmaxf(a0[m][q] + bb0, 0.f);
      dst[row * LDH + w * 32 + 16 + r] = (_Float16)fmaxf(a1[m][q] + bb1, 0.f);
    }
}

// ---------------------------------------------------------------------------
struct EdgeP {
  const float* edge_attr; const int* edge_index; const int* batch;
  const _Float16* x_h; const _Float16* u_h; const _Float16* wp;
  const float *eBin, *eBh, *eBout, *eG, *eBt;
  const float *aBin, *aBh, *aBout, *aG, *aBt;
  float* agg;
};

__global__ __launch_bounds__(256, 2) void edge_kernel(EdgeP p) {
  __shared__ __align__(16) _Float16 sIn[64 * LD1];
  __shared__ __align__(16) _Float16 sQ[64 * LDH];
  __shared__ __align__(16) _Float16 sR[64 * LDH];
  __shared__ int sSrc[64], sTgt[64], sEb[64];
  const int tid = threadIdx.x;
  const int e0 = blockIdx.x * 64;

  if (tid < 64) {
    int s = p.edge_index[e0 + tid];
    sSrc[tid] = s;
    sTgt[tid] = p.edge_index[N_EDGES + e0 + tid];
    sEb[tid] = p.batch[s];
  }
  __syncthreads();

  // stage neigh = [x[src] | x[tgt] | edge_attr | u[eb] | zero-pad] as f16
  for (int idx = tid; idx < 64 * 32; idx += 256) {
    int c = idx & 31, e = idx >> 5;
    if (c >= 29) continue;
    int col = c * 8;
    half8 v;
    if (col < 64) {
      v = *(const half8*)(p.x_h + (size_t)sSrc[e] * 64 + col);
    } else if (col < 128) {
      v = *(const half8*)(p.x_h + (size_t)sTgt[e] * 64 + col - 64);
    } else if (col < 192) {
      const float* ea = p.edge_attr + (size_t)(e0 + e) * 64 + (col - 128);
      float4 f0 = *(const float4*)ea, f1 = *(const float4*)(ea + 4);
      v[0] = (_Float16)f0.x; v[1] = (_Float16)f0.y;
      v[2] = (_Float16)f0.z; v[3] = (_Float16)f0.w;
      v[4] = (_Float16)f1.x; v[5] = (_Float16)f1.y;
      v[6] = (_Float16)f1.z; v[7] = (_Float16)f1.w;
    } else if (col < 208) {
      v = *(const half8*)(p.u_h + sEb[e] * 16 + col - 192);
    } else {
#pragma unroll
      for (int j = 0; j < 8; ++j) v[j] = (_Float16)0.f;
    }
    *(half8*)(sIn + e * LD1 + col) = v;
  }
  __syncthreads();

  const int lane = tid & 63, w = tid >> 6;
  _Float16* sP = sIn;  // reused after L1

  gemm_l1_dual(sIn, sQ, sR, p.wp + O_EW1, p.wp + O_AW1, p.eBin, p.aBin, w, lane);
  __syncthreads();
  gemm_h(sQ, sP, p.wp + O_EH0, p.eBh, w, lane);        __syncthreads();
  gemm_h(sR, sQ, p.wp + O_AH0, p.aBh, w, lane);        __syncthreads();
  gemm_h(sP, sR, p.wp + O_EH1, p.eBh + 128, w, lane);  __syncthreads();
  gemm_h(sQ, sP, p.wp + O_AH1, p.aBh + 128, w, lane);  __syncthreads();

  // output layer: wave owns rows [w*16, w*16+16), all 64 cols. e from sR, a from sP.
  const int r = lane & 15, ch = lane >> 4;
  const half8* wpEo = (const half8*)(p.wp + O_EWO);
  const half8* wpAo = (const half8*)(p.wp + O_AWO);
  f32x4 accE[4], accA[4];
#pragma unroll
  for (int t = 0; t < 4; ++t) {
    accE[t] = (f32x4){0.f, 0.f, 0.f, 0.f};
    accA[t] = (f32x4){0.f, 0.f, 0.f, 0.f};
  }
#pragma unroll
  for (int s = 0; s < 4; ++s) {
    half8 hE = *(const half8*)(sR + (w * 16 + r) * LDH + s * 32 + ch * 8);
    half8 hA = *(const half8*)(sP + (w * 16 + r) * LDH + s * 32 + ch * 8);
#pragma unroll
    for (int t = 0; t < 4; ++t) {
      half8 bEf = wpEo[(s * 4 + ch) * 64 + t * 16 + r];
      half8 bAf = wpAo[(s * 4 + ch) * 64 + t * 16 + r];
      accE[t] = mfma16(hE, bEf, accE[t]);
      accA[t] = mfma16(hA, bAf, accA[t]);
    }
  }
  float gE[4], tE[4], gA[4], tA[4];
#pragma unroll
  for (int t = 0; t < 4; ++t) {
    int cidx = t * 16 + r;
    float boE = p.eBout[cidx], boA = p.aBout[cidx];
#pragma unroll
    for (int q = 0; q < 4; ++q) { accE[t][q] += boE; accA[t][q] += boA; }
    gE[t] = p.eG[cidx]; tE[t] = p.eBt[cidx];
    gA[t] = p.aG[cidx]; tA[t] = p.aBt[cidx];
  }
#pragma unroll
  for (int q = 0; q < 4; ++q) {
    float s1e = 0.f, s2e = 0.f, s1a = 0.f, s2a = 0.f;
#pragma unroll
    for (int t = 0; t < 4; ++t) {
      float v = accE[t][q]; s1e += v; s2e += v * v;
      float u = accA[t][q]; s1a += u; s2a += u * u;
    }
#pragma unroll
    for (int mk = 1; mk < 16; mk <<= 1) {
      s1e += __shfl_xor(s1e, mk); s2e += __shfl_xor(s2e, mk);
      s1a += __shfl_xor(s1a, mk); s2a += __shfl_xor(s2a, mk);
    }
    float mue = s1e * (1.f / 64), mua = s1a * (1.f / 64);
    float rse = rsqrtf(s2e * (1.f / 64) - mue * mue + 1e-5f);
    float rsa = rsqrtf(s2a * (1.f / 64) - mua * mua + 1e-5f);
    int row = w * 16 + ch * 4 + q;
    float* ap = p.agg + (size_t)sTgt[row] * 64 + r;
#pragma unroll
    for (int t = 0; t < 4; ++t) {
      float oe = (accE[t][q] - mue) * rse * gE[t] + tE[t];
      float oa = (accA[t][q] - mua) * rsa * gA[t] + tA[t];
      atomicAdd(ap + t * 16, oe / (1.f + __expf(-oa)));
    }
  }
}

// ---------------------------------------------------------------------------
struct NodeP {
  const float* agg; const _Float16* x_h; const _Float16* u_h;
  const _Float16* wp; const int* batch;
  const float *Bin, *Bh, *Bout, *G, *Bt;
  float* out;
};

__global__ __launch_bounds__(256, 2) void node_kernel(NodeP p) {
  __shared__ __align__(16) _Float16 sIn[64 * LDN];
  __shared__ __align__(16) _Float16 sQ[64 * LDH];
  __shared__ int sB[64];
  const int tid = threadIdx.x;
  const int n0 = blockIdx.x * 64;

  if (tid < 64) {
    int n = n0 + tid;
    sB[tid] = (n < N_NODES) ? p.batch[n] : 0;
  }
  __syncthreads();

  for (int idx = tid; idx < 64 * 32; idx += 256) {
    int c = idx & 31, e = idx >> 5;
    if (c >= 21) continue;
    int n = n0 + e, col = c * 8;
    half8 v;
    if (n >= N_NODES || col >= 144) {
#pragma unroll
      for (int j = 0; j < 8; ++j) v[j] = (_Float16)0.f;
    } else if (col < 64) {
      v = *(const half8*)(p.x_h + (size_t)n * 64 + col);
    } else if (col < 128) {
      const float* ag = p.agg + (size_t)n * 64 + (col - 64);
      float4 f0 = *(const float4*)ag, f1 = *(const float4*)(ag + 4);
      v[0] = (_Float16)f0.x; v[1] = (_Float16)f0.y;
      v[2] = (_Float16)f0.z; v[3] = (_Float16)f0.w;
      v[4] = (_Float16)f1.x; v[5] = (_Float16)f1.y;
      v[6] = (_Float16)f1.z; v[7] = (_Float16)f1.w;
    } else {
      v = *(const half8*)(p.u_h + sB[e] * 16 + col - 128);
    }
    *(half8*)(sIn + e * LDN + col) = v;
  }
  __syncthreads();

  const int lane = tid & 63, w = tid >> 6;
  _Float16* sP = sIn;

  gemm_l1n(sIn, sQ, p.wp + O_NW1, p.Bin, w, lane);      __syncthreads();
  gemm_h(sQ, sP, p.wp + O_NH0, p.Bh, w, lane);          __syncthreads();
  gemm_h(sP, sQ, p.wp + O_NH1, p.Bh + 128, w, lane);    __syncthreads();

  const int r = lane & 15, ch = lane >> 4;
  const half8* wpNo = (const half8*)(p.wp + O_NWO);
  f32x4 acc[4];
#pragma unroll
  for (int t = 0; t < 4; ++t) acc[t] = (f32x4){0.f, 0.f, 0.f, 0.f};
#pragma unroll
  for (int s = 0; s < 4; ++s) {
    half8 h = *(const half8*)(sQ + (w * 16 + r) * LDH + s * 32 + ch * 8);
#pragma unroll
    for (int t = 0; t < 4; ++t) {
      half8 b = wpNo[(s * 4 + ch) * 64 + t * 16 + r];
      acc[t] = mfma16(h, b, acc[t]);
    }
  }
  float g[4], bt[4];
#pragma unroll
  for (int t = 0; t < 4; ++t) {
    int cidx = t * 16 + r;
    float bo = p.Bout[cidx];
#pragma unroll
    for (int q = 0; q < 4; ++q) acc[t][q] += bo;
    g[t] = p.G[cidx]; bt[t] = p.Bt[cidx];
  }
#pragma unroll
  for (int q = 0; q < 4; ++q) {
    float s1 = 0.f, s2 = 0.f;
#pragma unroll
    for (int t = 0; t < 4; ++t) { float v = acc[t][q]; s1 += v; s2 += v * v; }
#pragma unroll
    for (int mk = 1; mk < 16; mk <<= 1) {
      s1 += __shfl_xor(s1, mk); s2 += __shfl_xor(s2, mk);
    }
    float mu = s1 * (1.f / 64);
    float rs = rsqrtf(s2 * (1.f / 64) - mu * mu + 1e-5f);
    int row = w * 16 + ch * 4 + q;
    int n = n0 + row;
    if (n < N_NODES) {
#pragma unroll
      for (int t = 0; t < 4; ++t)
        p.out[(size_t)n * 64 + t * 16 + r] = (acc[t][q] - mu) * rs * g[t] + bt[t];
    }
  }
}

// ---------------------------------------------------------------------------
// Per-call pack: fp32 weights -> MFMA-B-fragment-packed fp16; x,u -> fp16.
// Packed layout: wdst[((s*4+c)*N + n)*8 + j] = W[s*32+c*8+j][n] (0 if k>=Kreal)
// ---------------------------------------------------------------------------
#define GX 112
struct PackP {
  const float* src[12];
  int Kreal[12], Nlog[12], size[12], dstoff[12];
  const float* x; const float* u;
  _Float16* x_h; _Float16* u_h; _Float16* wdst;
};

__global__ void pack_kernel(PackP p) {
  int y = blockIdx.y;
  int idx = blockIdx.x * 256 + threadIdx.x;
  if (y < 12) {
    int sz = p.size[y];
    if (idx >= sz) return;
    int N = 1 << p.Nlog[y];
    int j = idx & 7, t = idx >> 3;
    int n = t & (N - 1);
    int sc = t >> p.Nlog[y];
    int c = sc & 3, s = sc >> 2;
    int k = s * 32 + c * 8 + j;
    p.wdst[p.dstoff[y] + idx] =
        (k < p.Kreal[y]) ? (_Float16)p.src[y][k * N + n] : (_Float16)0.f;
  } else {
    for (int i = idx; i < N_NODES * 64; i += GX * 256) p.x_h[i] = (_Float16)p.x[i];
    for (int i = idx; i < 64 * 16; i += GX * 256) p.u_h[i] = (_Float16)p.u[i];
  }
}

// ---------------------------------------------------------------------------
extern "C" void kernel_launch(void* const* d_in, const int* in_sizes, int n_in,
                              void* d_out, int out_size, void* d_ws, size_t ws_size,
                              hipStream_t stream) {
  const float* x = (const float*)d_in[0];
  const float* edge_attr = (const float*)d_in[1];
  const float* u = (const float*)d_in[2];
  const int* edge_index = (const int*)d_in[3];
  const int* batch = (const int*)d_in[4];

  char* ws = (char*)d_ws;
  float* agg = (float*)(ws + AGG_OFF);
  _Float16* x_h = (_Float16*)(ws + XH_OFF);
  _Float16* u_h = (_Float16*)(ws + UH_OFF);
  _Float16* wp = (_Float16*)(ws + WP_OFF);

  hipMemsetAsync(agg, 0, (size_t)N_NODES * 64 * sizeof(float), stream);

  PackP pk;
  const float* eWh = (const float*)d_in[7];
  const float* aWh = (const float*)d_in[15];
  const float* nWh = (const float*)d_in[23];
  const float* srcs[12] = {
      (const float*)d_in[5], eWh, eWh + 16384, (const float*)d_in[9],
      (const float*)d_in[13], aWh, aWh + 16384, (const float*)d_in[17],
      (const float*)d_in[21], nWh, nWh + 16384, (const float*)d_in[25]};
  const int kr[12] = {208, 128, 128, 128, 208, 128, 128, 128, 144, 128, 128, 128};
  const int nl[12] = {7, 7, 7, 6, 7, 7, 7, 6, 7, 7, 7, 6};
  const int sz[12] = {28672, 16384, 16384, 8192, 28672, 16384, 16384, 8192,
                      20480, 16384, 16384, 8192};
  const int off[12] = {O_EW1, O_EH0, O_EH1, O_EWO, O_AW1, O_AH0, O_AH1, O_AWO,
                       O_NW1, O_NH0, O_NH1, O_NWO};
  for (int i = 0; i < 12; ++i) {
    pk.src[i] = srcs[i]; pk.Kreal[i] = kr[i]; pk.Nlog[i] = nl[i];
    pk.size[i] = sz[i]; pk.dstoff[i] = off[i];
  }
  pk.x = x; pk.u = u; pk.x_h = x_h; pk.u_h = u_h; pk.wdst = wp;
  pack_kernel<<<dim3(GX, 13), 256, 0, stream>>>(pk);

  EdgeP ep;
  ep.edge_attr = edge_attr; ep.edge_index = edge_index; ep.batch = batch;
  ep.x_h = x_h; ep.u_h = u_h; ep.wp = wp;
  ep.eBin = (const float*)d_in[6];  ep.eBh = (const float*)d_in[8];
  ep.eBout = (const float*)d_in[10]; ep.eG = (const float*)d_in[11];
  ep.eBt = (const float*)d_in[12];
  ep.aBin = (const float*)d_in[14]; ep.aBh = (const float*)d_in[16];
  ep.aBout = (const float*)d_in[18]; ep.aG = (const float*)d_in[19];
  ep.aBt = (const float*)d_in[20];
  ep.agg = agg;
  edge_kernel<<<N_EDGES / 64, 256, 0, stream>>>(ep);

  NodeP np;
  np.agg = agg; np.x_h = x_h; np.u_h = u_h; np.wp = wp; np.batch = batch;
  np.Bin = (const float*)d_in[22]; np.Bh = (const float*)d_in[24];
  np.Bout = (const float*)d_in[26]; np.G = (const float*)d_in[27];
  np.Bt = (const float*)d_in[28];
  np.out = (float*)d_out;
  node_kernel<<<(N_NODES + 63) / 64, 256, 0, stream>>>(np);
}

// Round 3
// 551.299 us; speedup vs baseline: 5.6547x; 1.0782x over previous
//
#include <hip/hip_runtime.h>
#include <math.h>

#define N_NODES 50000
#define N_EDGES 400000

typedef _Float16 half8 __attribute__((ext_vector_type(8)));
typedef float f32x4 __attribute__((ext_vector_type(4)));

#define LD1 232   // edge L1 input ld (K=208 padded to 224, +8 bank pad)
#define LDH 136   // hidden activation ld (128 + 8 pad)
#define LDN 168   // node L1 input ld (K=144 padded to 160, +8 pad)

// workspace layout (bytes)
#define AGG_OFF 0           // 50000*64 f32 = 12.8 MB
#define XH_OFF  12800000    // 50000*64 f16
#define UH_OFF  19200000    // 64*16 f16
#define WP_OFF  19202048    // packed weights, 200704 f16
// packed-weight offsets (f16 elements)
#define O_EW1 0
#define O_EH0 28672
#define O_EH1 45056
#define O_EWO 61440
#define O_AW1 69632
#define O_AH0 98304
#define O_AH1 114688
#define O_AWO 131072
#define O_NW1 139264
#define O_NH0 159744
#define O_NH1 176128
#define O_NWO 192512

__device__ __forceinline__ f32x4 mfma16(half8 a, half8 b, f32x4 c) {
  return __builtin_amdgcn_mfma_f32_16x16x32_f16(a, b, c, 0, 0, 0);
}

// ---------------------------------------------------------------------------
// 32-col GEMM slice: dst[rows 0..63][w*32..w*32+32) = relu(src @ W + b), f16.
// NS k-steps of 32. dst ld = LDH. B from packed global (L2-resident).
// ---------------------------------------------------------------------------
template<int NS, int LDSRC>
__device__ __forceinline__ void gemm32(const _Float16* __restrict__ src,
                                       _Float16* __restrict__ dst,
                                       const _Float16* __restrict__ wp16,
                                       const float* __restrict__ bias,
                                       int w, int lane) {
  const half8* wp = (const half8*)wp16;
  const int r = lane & 15, ch = lane >> 4;
  f32x4 a0[4], a1[4];
#pragma unroll
  for (int m = 0; m < 4; ++m) {
    a0[m] = (f32x4){0.f, 0.f, 0.f, 0.f};
    a1[m] = (f32x4){0.f, 0.f, 0.f, 0.f};
  }
#pragma unroll
  for (int s = 0; s < NS; ++s) {
    half8 b0 = wp[(s * 4 + ch) * 128 + w * 32 + r];
    half8 b1 = wp[(s * 4 + ch) * 128 + w * 32 + 16 + r];
#pragma unroll
    for (int m = 0; m < 4; ++m) {
      half8 a = *(const half8*)(src + (m * 16 + r) * LDSRC + s * 32 + ch * 8);
      a0[m] = mfma16(a, b0, a0[m]);
      a1[m] = mfma16(a, b1, a1[m]);
    }
  }
  float bb0 = bias[w * 32 + r], bb1 = bias[w * 32 + 16 + r];
#pragma unroll
  for (int m = 0; m < 4; ++m)
#pragma unroll
    for (int q = 0; q < 4; ++q) {
      int row = m * 16 + ch * 4 + q;
      dst[row * LDH + w * 32 + r]      = (_Float16)fmaxf(a0[m][q] + bb0, 0.f);
      dst[row * LDH + w * 32 + 16 + r] = (_Float16)fmaxf(a1[m][q] + bb1, 0.f);
    }
}

// ---------------------------------------------------------------------------
struct EdgeP {
  const float* edge_attr; const int* edge_index; const int* batch;
  const _Float16* x_h; const _Float16* u_h; const _Float16* wp;
  const float *eBin, *eBh, *eBout, *eG, *eBt;
  const float *aBin, *aBh, *aBout, *aG, *aBt;
  float* agg;
};

// 64 edges/block, 512 threads. Waves 0-3: e-MLP; waves 4-7: a-MLP (concurrent).
// LDS exactly 81920 B -> 2 blocks/CU (16 waves/CU).
//   sIn [64*232] f16: L1 input; reused (ld=LDH) as e-path pong after L1.
//   sQe/sQa [64*136]: e/a ping; sPa [64*136]: a pong, reused as f32 combine buf.
__global__ __launch_bounds__(512, 4) void edge_kernel(EdgeP p) {
  __shared__ __align__(16) _Float16 sIn[64 * LD1];
  __shared__ __align__(16) _Float16 sQe[64 * LDH];
  __shared__ __align__(16) _Float16 sQa[64 * LDH];
  __shared__ __align__(16) _Float16 sPa[64 * LDH];
  const int tid = threadIdx.x;
  const int e0 = blockIdx.x * 64;

  // stage neigh = [x[src] | x[tgt] | edge_attr | u[batch[src]] | 0-pad] as f16
  for (int idx = tid; idx < 64 * 32; idx += 512) {
    int c = idx & 31, e = idx >> 5;
    if (c >= 28) continue;
    int col = c * 8;
    half8 v;
    if (col < 64) {
      int s = p.edge_index[e0 + e];
      v = *(const half8*)(p.x_h + (size_t)s * 64 + col);
    } else if (col < 128) {
      int t = p.edge_index[N_EDGES + e0 + e];
      v = *(const half8*)(p.x_h + (size_t)t * 64 + col - 64);
    } else if (col < 192) {
      const float* ea = p.edge_attr + (size_t)(e0 + e) * 64 + (col - 128);
      float4 f0 = *(const float4*)ea, f1 = *(const float4*)(ea + 4);
      v[0] = (_Float16)f0.x; v[1] = (_Float16)f0.y;
      v[2] = (_Float16)f0.z; v[3] = (_Float16)f0.w;
      v[4] = (_Float16)f1.x; v[5] = (_Float16)f1.y;
      v[6] = (_Float16)f1.z; v[7] = (_Float16)f1.w;
    } else if (col < 208) {
      int s = p.edge_index[e0 + e];
      int eb = p.batch[s];
      v = *(const half8*)(p.u_h + eb * 16 + col - 192);
    } else {
#pragma unroll
      for (int j = 0; j < 8; ++j) v[j] = (_Float16)0.f;
    }
    *(half8*)(sIn + e * LD1 + col) = v;
  }
  __syncthreads();

  const int lane = tid & 63, wid = tid >> 6, we = wid & 3;
  const bool isE = wid < 4;
  _Float16* ping = isE ? sQe : sQa;
  _Float16* pong = isE ? sIn : sPa;   // sIn reused with ld=LDH after L1
  const _Float16* w1 = p.wp + (isE ? O_EW1 : O_AW1);
  const _Float16* h0 = p.wp + (isE ? O_EH0 : O_AH0);
  const _Float16* h1 = p.wp + (isE ? O_EH1 : O_AH1);
  const _Float16* wo = p.wp + (isE ? O_EWO : O_AWO);
  const float* bin = isE ? p.eBin : p.aBin;
  const float* bh  = isE ? p.eBh  : p.aBh;
  const float* bo  = isE ? p.eBout: p.aBout;
  const float* g   = isE ? p.eG   : p.aG;
  const float* bt  = isE ? p.eBt  : p.aBt;

  gemm32<7, LD1>(sIn,  ping, w1, bin,      we, lane); __syncthreads();
  gemm32<4, LDH>(ping, pong, h0, bh,       we, lane); __syncthreads();
  gemm32<4, LDH>(pong, ping, h1, bh + 128, we, lane); __syncthreads();

  // output layer: wave owns rows [we*16, we*16+16), all 64 cols, from `ping`
  const int r = lane & 15, ch = lane >> 4;
  const half8* wpo = (const half8*)wo;
  f32x4 acc[4];
#pragma unroll
  for (int t = 0; t < 4; ++t) acc[t] = (f32x4){0.f, 0.f, 0.f, 0.f};
#pragma unroll
  for (int s = 0; s < 4; ++s) {
    half8 a = *(const half8*)(ping + (we * 16 + r) * LDH + s * 32 + ch * 8);
#pragma unroll
    for (int t = 0; t < 4; ++t)
      acc[t] = mfma16(a, wpo[(s * 4 + ch) * 64 + t * 16 + r], acc[t]);
  }
  float gg[4], tt[4];
#pragma unroll
  for (int t = 0; t < 4; ++t) {
    int cidx = t * 16 + r;
    float bov = bo[cidx];
#pragma unroll
    for (int q = 0; q < 4; ++q) acc[t][q] += bov;
    gg[t] = g[cidx]; tt[t] = bt[cidx];
  }
  // LayerNorm stats per row (16 lanes * 4 t cover the 64 features)
  float mu_[4], rs_[4];
#pragma unroll
  for (int q = 0; q < 4; ++q) {
    float s1 = 0.f, s2 = 0.f;
#pragma unroll
    for (int t = 0; t < 4; ++t) { float v = acc[t][q]; s1 += v; s2 += v * v; }
#pragma unroll
    for (int mk = 1; mk < 16; mk <<= 1) {
      s1 += __shfl_xor(s1, mk); s2 += __shfl_xor(s2, mk);
    }
    mu_[q] = s1 * (1.f / 64);
    rs_[q] = rsqrtf(s2 * (1.f / 64) - mu_[q] * mu_[q] + 1e-5f);
  }
  float* cmb = (float*)sPa;  // a-pong no longer needed
  if (!isE) {
#pragma unroll
    for (int q = 0; q < 4; ++q) {
      int row = we * 16 + ch * 4 + q;
#pragma unroll
      for (int t = 0; t < 4; ++t) {
        float oa = (acc[t][q] - mu_[q]) * rs_[q] * gg[t] + tt[t];
        cmb[row * 64 + t * 16 + r] = 1.f / (1.f + __expf(-oa));
      }
    }
  }
  __syncthreads();
  if (isE) {
#pragma unroll
    for (int q = 0; q < 4; ++q) {
      int row = we * 16 + ch * 4 + q;
      int tgt = p.edge_index[N_EDGES + e0 + row];
      float* ap = p.agg + (size_t)tgt * 64 + r;
#pragma unroll
      for (int t = 0; t < 4; ++t) {
        float oe = (acc[t][q] - mu_[q]) * rs_[q] * gg[t] + tt[t];
        atomicAdd(ap + t * 16, oe * cmb[row * 64 + t * 16 + r]);
      }
    }
  }
}

// ---------------------------------------------------------------------------
struct NodeP {
  const float* agg; const _Float16* x_h; const _Float16* u_h;
  const _Float16* wp; const int* batch;
  const float *Bin, *Bh, *Bout, *G, *Bt;
  float* out;
};

__global__ __launch_bounds__(256, 2) void node_kernel(NodeP p) {
  __shared__ __align__(16) _Float16 sIn[64 * LDN];
  __shared__ __align__(16) _Float16 sQ[64 * LDH];
  __shared__ int sB[64];
  const int tid = threadIdx.x;
  const int n0 = blockIdx.x * 64;

  if (tid < 64) {
    int n = n0 + tid;
    sB[tid] = (n < N_NODES) ? p.batch[n] : 0;
  }
  __syncthreads();

  for (int idx = tid; idx < 64 * 32; idx += 256) {
    int c = idx & 31, e = idx >> 5;
    if (c >= 21) continue;
    int n = n0 + e, col = c * 8;
    half8 v;
    if (n >= N_NODES || col >= 144) {
#pragma unroll
      for (int j = 0; j < 8; ++j) v[j] = (_Float16)0.f;
    } else if (col < 64) {
      v = *(const half8*)(p.x_h + (size_t)n * 64 + col);
    } else if (col < 128) {
      const float* ag = p.agg + (size_t)n * 64 + (col - 64);
      float4 f0 = *(const float4*)ag, f1 = *(const float4*)(ag + 4);
      v[0] = (_Float16)f0.x; v[1] = (_Float16)f0.y;
      v[2] = (_Float16)f0.z; v[3] = (_Float16)f0.w;
      v[4] = (_Float16)f1.x; v[5] = (_Float16)f1.y;
      v[6] = (_Float16)f1.z; v[7] = (_Float16)f1.w;
    } else {
      v = *(const half8*)(p.u_h + sB[e] * 16 + col - 128);
    }
    *(half8*)(sIn + e * LDN + col) = v;
  }
  __syncthreads();

  const int lane = tid & 63, w = tid >> 6;
  _Float16* sP = sIn;

  gemm32<5, LDN>(sIn, sQ, p.wp + O_NW1, p.Bin, w, lane);      __syncthreads();
  gemm32<4, LDH>(sQ, sP, p.wp + O_NH0, p.Bh, w, lane);        __syncthreads();
  gemm32<4, LDH>(sP, sQ, p.wp + O_NH1, p.Bh + 128, w, lane);  __syncthreads();

  const int r = lane & 15, ch = lane >> 4;
  const half8* wpNo = (const half8*)(p.wp + O_NWO);
  f32x4 acc[4];
#pragma unroll
  for (int t = 0; t < 4; ++t) acc[t] = (f32x4){0.f, 0.f, 0.f, 0.f};
#pragma unroll
  for (int s = 0; s < 4; ++s) {
    half8 h = *(const half8*)(sQ + (w * 16 + r) * LDH + s * 32 + ch * 8);
#pragma unroll
    for (int t = 0; t < 4; ++t) {
      half8 b = wpNo[(s * 4 + ch) * 64 + t * 16 + r];
      acc[t] = mfma16(h, b, acc[t]);
    }
  }
  float g[4], bt[4];
#pragma unroll
  for (int t = 0; t < 4; ++t) {
    int cidx = t * 16 + r;
    float bov = p.Bout[cidx];
#pragma unroll
    for (int q = 0; q < 4; ++q) acc[t][q] += bov;
    g[t] = p.G[cidx]; bt[t] = p.Bt[cidx];
  }
#pragma unroll
  for (int q = 0; q < 4; ++q) {
    float s1 = 0.f, s2 = 0.f;
#pragma unroll
    for (int t = 0; t < 4; ++t) { float v = acc[t][q]; s1 += v; s2 += v * v; }
#pragma unroll
    for (int mk = 1; mk < 16; mk <<= 1) {
      s1 += __shfl_xor(s1, mk); s2 += __shfl_xor(s2, mk);
    }
    float mu = s1 * (1.f / 64);
    float rs = rsqrtf(s2 * (1.f / 64) - mu * mu + 1e-5f);
    int row = w * 16 + ch * 4 + q;
    int n = n0 + row;
    if (n < N_NODES) {
#pragma unroll
      for (int t = 0; t < 4; ++t)
        p.out[(size_t)n * 64 + t * 16 + r] = (acc[t][q] - mu) * rs * g[t] + bt[t];
    }
  }
}

// ---------------------------------------------------------------------------
// Per-call pack: fp32 weights -> MFMA-B-fragment-packed fp16; x,u -> fp16.
// Packed layout: wdst[((s*4+c)*N + n)*8 + j] = W[s*32+c*8+j][n] (0 if k>=Kreal)
// ---------------------------------------------------------------------------
#define GX 112
struct PackP {
  const float* src[12];
  int Kreal[12], Nlog[12], size[12], dstoff[12];
  const float* x; const float* u;
  _Float16* x_h; _Float16* u_h; _Float16* wdst;
};

__global__ void pack_kernel(PackP p) {
  int y = blockIdx.y;
  int idx = blockIdx.x * 256 + threadIdx.x;
  if (y < 12) {
    int sz = p.size[y];
    if (idx >= sz) return;
    int N = 1 << p.Nlog[y];
    int j = idx & 7, t = idx >> 3;
    int n = t & (N - 1);
    int sc = t >> p.Nlog[y];
    int c = sc & 3, s = sc >> 2;
    int k = s * 32 + c * 8 + j;
    p.wdst[p.dstoff[y] + idx] =
        (k < p.Kreal[y]) ? (_Float16)p.src[y][k * N + n] : (_Float16)0.f;
  } else {
    for (int i = idx; i < N_NODES * 64; i += GX * 256) p.x_h[i] = (_Float16)p.x[i];
    for (int i = idx; i < 64 * 16; i += GX * 256) p.u_h[i] = (_Float16)p.u[i];
  }
}

// ---------------------------------------------------------------------------
extern "C" void kernel_launch(void* const* d_in, const int* in_sizes, int n_in,
                              void* d_out, int out_size, void* d_ws, size_t ws_size,
                              hipStream_t stream) {
  const float* x = (const float*)d_in[0];
  const float* edge_attr = (const float*)d_in[1];
  const float* u = (const float*)d_in[2];
  const int* edge_index = (const int*)d_in[3];
  const int* batch = (const int*)d_in[4];

  char* ws = (char*)d_ws;
  float* agg = (float*)(ws + AGG_OFF);
  _Float16* x_h = (_Float16*)(ws + XH_OFF);
  _Float16* u_h = (_Float16*)(ws + UH_OFF);
  _Float16* wp = (_Float16*)(ws + WP_OFF);

  hipMemsetAsync(agg, 0, (size_t)N_NODES * 64 * sizeof(float), stream);

  PackP pk;
  const float* eWh = (const float*)d_in[7];
  const float* aWh = (const float*)d_in[15];
  const float* nWh = (const float*)d_in[23];
  const float* srcs[12] = {
      (const float*)d_in[5], eWh, eWh + 16384, (const float*)d_in[9],
      (const float*)d_in[13], aWh, aWh + 16384, (const float*)d_in[17],
      (const float*)d_in[21], nWh, nWh + 16384, (const float*)d_in[25]};
  const int kr[12] = {208, 128, 128, 128, 208, 128, 128, 128, 144, 128, 128, 128};
  const int nl[12] = {7, 7, 7, 6, 7, 7, 7, 6, 7, 7, 7, 6};
  const int sz[12] = {28672, 16384, 16384, 8192, 28672, 16384, 16384, 8192,
                      20480, 16384, 16384, 8192};
  const int off[12] = {O_EW1, O_EH0, O_EH1, O_EWO, O_AW1, O_AH0, O_AH1, O_AWO,
                       O_NW1, O_NH0, O_NH1, O_NWO};
  for (int i = 0; i < 12; ++i) {
    pk.src[i] = srcs[i]; pk.Kreal[i] = kr[i]; pk.Nlog[i] = nl[i];
    pk.size[i] = sz[i]; pk.dstoff[i] = off[i];
  }
  pk.x = x; pk.u = u; pk.x_h = x_h; pk.u_h = u_h; pk.wdst = wp;
  pack_kernel<<<dim3(GX, 13), 256, 0, stream>>>(pk);

  EdgeP ep;
  ep.edge_attr = edge_attr; ep.edge_index = edge_index; ep.batch = batch;
  ep.x_h = x_h; ep.u_h = u_h; ep.wp = wp;
  ep.eBin = (const float*)d_in[6];  ep.eBh = (const float*)d_in[8];
  ep.eBout = (const float*)d_in[10]; ep.eG = (const float*)d_in[11];
  ep.eBt = (const float*)d_in[12];
  ep.aBin = (const float*)d_in[14]; ep.aBh = (const float*)d_in[16];
  ep.aBout = (const float*)d_in[18]; ep.aG = (const float*)d_in[19];
  ep.aBt = (const float*)d_in[20];
  ep.agg = agg;
  edge_kernel<<<N_EDGES / 64, 512, 0, stream>>>(ep);

  NodeP np;
  np.agg = agg; np.x_h = x_h; np.u_h = u_h; np.wp = wp; np.batch = batch;
  np.Bin = (const float*)d_in[22]; np.Bh = (const float*)d_in[24];
  np.Bout = (const float*)d_in[26]; np.G = (const float*)d_in[27];
  np.Bt = (const float*)d_in[28];
  np.out = (float*)d_out;
  node_kernel<<<(N_NODES + 63) / 64, 256, 0, stream>>>(np);
}

// Round 4
// 550.775 us; speedup vs baseline: 5.6601x; 1.0010x over previous
//
#include <hip/hip_runtime.h>
#include <math.h>

#define N_NODES 50000
#define N_EDGES 400000

typedef _Float16 half8 __attribute__((ext_vector_type(8)));
typedef float f32x4 __attribute__((ext_vector_type(4)));

#define LD1 232   // edge L1 input ld (K=208 padded to 224, +8 bank pad)
#define LDH 136   // hidden activation ld (128 + 8 pad)
#define LDN 168   // node L1 input ld (K=144 padded to 160, +8 pad)

// workspace layout (bytes)
#define AGG_OFF 0           // 50000*64 f32 = 12.8 MB
#define XH_OFF  12800000    // 50000*64 f16
#define UH_OFF  19200000    // 64*16 f16
#define WP_OFF  19202048    // packed weights, 200704 f16
// packed-weight offsets (f16 elements)
#define O_EW1 0
#define O_EH0 28672
#define O_EH1 45056
#define O_EWO 61440
#define O_AW1 69632
#define O_AH0 98304
#define O_AH1 114688
#define O_AWO 131072
#define O_NW1 139264
#define O_NH0 159744
#define O_NH1 176128
#define O_NWO 192512

__device__ __forceinline__ f32x4 mfma16(half8 a, half8 b, f32x4 c) {
  return __builtin_amdgcn_mfma_f32_16x16x32_f16(a, b, c, 0, 0, 0);
}

// ---------------------------------------------------------------------------
// 32-col GEMM slice: dst[rows 0..63][w*32..w*32+32) = relu(src @ W + b), f16.
// ALL B-fragments preloaded into registers first (static-indexed arrays) so
// the NS*2 L2 loads issue back-to-back and their latency overlaps once.
// ---------------------------------------------------------------------------
template<int NS, int LDSRC>
__device__ __forceinline__ void gemm32(const _Float16* __restrict__ src,
                                       _Float16* __restrict__ dst,
                                       const _Float16* __restrict__ wp16,
                                       const float* __restrict__ bias,
                                       int w, int lane) {
  const half8* wp = (const half8*)wp16;
  const int r = lane & 15, ch = lane >> 4;
  half8 B0[NS], B1[NS];
#pragma unroll
  for (int s = 0; s < NS; ++s) {
    B0[s] = wp[(s * 4 + ch) * 128 + w * 32 + r];
    B1[s] = wp[(s * 4 + ch) * 128 + w * 32 + 16 + r];
  }
  f32x4 a0[4], a1[4];
#pragma unroll
  for (int m = 0; m < 4; ++m) {
    a0[m] = (f32x4){0.f, 0.f, 0.f, 0.f};
    a1[m] = (f32x4){0.f, 0.f, 0.f, 0.f};
  }
#pragma unroll
  for (int s = 0; s < NS; ++s) {
#pragma unroll
    for (int m = 0; m < 4; ++m) {
      half8 a = *(const half8*)(src + (m * 16 + r) * LDSRC + s * 32 + ch * 8);
      a0[m] = mfma16(a, B0[s], a0[m]);
      a1[m] = mfma16(a, B1[s], a1[m]);
    }
  }
  float bb0 = bias[w * 32 + r], bb1 = bias[w * 32 + 16 + r];
#pragma unroll
  for (int m = 0; m < 4; ++m)
#pragma unroll
    for (int q = 0; q < 4; ++q) {
      int row = m * 16 + ch * 4 + q;
      dst[row * LDH + w * 32 + r]      = (_Float16)fmaxf(a0[m][q] + bb0, 0.f);
      dst[row * LDH + w * 32 + 16 + r] = (_Float16)fmaxf(a1[m][q] + bb1, 0.f);
    }
}

// ---------------------------------------------------------------------------
struct EdgeP {
  const float* edge_attr; const int* edge_index; const int* batch;
  const _Float16* x_h; const _Float16* u_h; const _Float16* wp;
  const float *eBin, *eBh, *eBout, *eG, *eBt;
  const float *aBin, *aBh, *aBout, *aG, *aBt;
  float* agg;
};

// 64 edges/block, 512 threads. Waves 0-3: e-MLP; waves 4-7: a-MLP (concurrent).
// LDS exactly 81920 B -> 2 blocks/CU (16 waves/CU).
__global__ __launch_bounds__(512, 4) void edge_kernel(EdgeP p) {
  __shared__ __align__(16) _Float16 sIn[64 * LD1];
  __shared__ __align__(16) _Float16 sQe[64 * LDH];
  __shared__ __align__(16) _Float16 sQa[64 * LDH];
  __shared__ __align__(16) _Float16 sPa[64 * LDH];
  const int tid = threadIdx.x;
  const int e0 = blockIdx.x * 64;

  // stage neigh = [x[src] | x[tgt] | edge_attr | u[batch[src]] | 0-pad] as f16
  for (int idx = tid; idx < 64 * 32; idx += 512) {
    int c = idx & 31, e = idx >> 5;
    if (c >= 28) continue;
    int col = c * 8;
    half8 v;
    if (col < 64) {
      int s = p.edge_index[e0 + e];
      v = *(const half8*)(p.x_h + (size_t)s * 64 + col);
    } else if (col < 128) {
      int t = p.edge_index[N_EDGES + e0 + e];
      v = *(const half8*)(p.x_h + (size_t)t * 64 + col - 64);
    } else if (col < 192) {
      const float* ea = p.edge_attr + (size_t)(e0 + e) * 64 + (col - 128);
      float4 f0 = *(const float4*)ea, f1 = *(const float4*)(ea + 4);
      v[0] = (_Float16)f0.x; v[1] = (_Float16)f0.y;
      v[2] = (_Float16)f0.z; v[3] = (_Float16)f0.w;
      v[4] = (_Float16)f1.x; v[5] = (_Float16)f1.y;
      v[6] = (_Float16)f1.z; v[7] = (_Float16)f1.w;
    } else if (col < 208) {
      int s = p.edge_index[e0 + e];
      int eb = p.batch[s];
      v = *(const half8*)(p.u_h + eb * 16 + col - 192);
    } else {
#pragma unroll
      for (int j = 0; j < 8; ++j) v[j] = (_Float16)0.f;
    }
    *(half8*)(sIn + e * LD1 + col) = v;
  }
  __syncthreads();

  const int lane = tid & 63, wid = tid >> 6, we = wid & 3;
  const bool isE = wid < 4;
  _Float16* ping = isE ? sQe : sQa;
  _Float16* pong = isE ? sIn : sPa;   // sIn reused with ld=LDH after L1
  const _Float16* w1 = p.wp + (isE ? O_EW1 : O_AW1);
  const _Float16* h0 = p.wp + (isE ? O_EH0 : O_AH0);
  const _Float16* h1 = p.wp + (isE ? O_EH1 : O_AH1);
  const _Float16* wo = p.wp + (isE ? O_EWO : O_AWO);
  const float* bin = isE ? p.eBin : p.aBin;
  const float* bh  = isE ? p.eBh  : p.aBh;
  const float* bo  = isE ? p.eBout: p.aBout;
  const float* g   = isE ? p.eG   : p.aG;
  const float* bt  = isE ? p.eBt  : p.aBt;

  gemm32<7, LD1>(sIn,  ping, w1, bin,      we, lane); __syncthreads();
  gemm32<4, LDH>(ping, pong, h0, bh,       we, lane); __syncthreads();
  gemm32<4, LDH>(pong, ping, h1, bh + 128, we, lane); __syncthreads();

  // output layer: wave owns rows [we*16, we*16+16), all 64 cols, from `ping`
  const int r = lane & 15, ch = lane >> 4;
  const half8* wpo = (const half8*)wo;
  half8 BO[4][4];
#pragma unroll
  for (int s = 0; s < 4; ++s)
#pragma unroll
    for (int t = 0; t < 4; ++t)
      BO[s][t] = wpo[(s * 4 + ch) * 64 + t * 16 + r];
  f32x4 acc[4];
#pragma unroll
  for (int t = 0; t < 4; ++t) acc[t] = (f32x4){0.f, 0.f, 0.f, 0.f};
#pragma unroll
  for (int s = 0; s < 4; ++s) {
    half8 a = *(const half8*)(ping + (we * 16 + r) * LDH + s * 32 + ch * 8);
#pragma unroll
    for (int t = 0; t < 4; ++t)
      acc[t] = mfma16(a, BO[s][t], acc[t]);
  }
  float gg[4], tt[4];
#pragma unroll
  for (int t = 0; t < 4; ++t) {
    int cidx = t * 16 + r;
    float bov = bo[cidx];
#pragma unroll
    for (int q = 0; q < 4; ++q) acc[t][q] += bov;
    gg[t] = g[cidx]; tt[t] = bt[cidx];
  }
  // LayerNorm stats per row (16 lanes * 4 t cover the 64 features)
  float mu_[4], rs_[4];
#pragma unroll
  for (int q = 0; q < 4; ++q) {
    float s1 = 0.f, s2 = 0.f;
#pragma unroll
    for (int t = 0; t < 4; ++t) { float v = acc[t][q]; s1 += v; s2 += v * v; }
#pragma unroll
    for (int mk = 1; mk < 16; mk <<= 1) {
      s1 += __shfl_xor(s1, mk); s2 += __shfl_xor(s2, mk);
    }
    mu_[q] = s1 * (1.f / 64);
    rs_[q] = rsqrtf(s2 * (1.f / 64) - mu_[q] * mu_[q] + 1e-5f);
  }
  float* cmb = (float*)sPa;  // a-pong no longer needed
  if (!isE) {
#pragma unroll
    for (int q = 0; q < 4; ++q) {
      int row = we * 16 + ch * 4 + q;
#pragma unroll
      for (int t = 0; t < 4; ++t) {
        float oa = (acc[t][q] - mu_[q]) * rs_[q] * gg[t] + tt[t];
        cmb[row * 64 + t * 16 + r] = 1.f / (1.f + __expf(-oa));
      }
    }
  }
  __syncthreads();
  if (isE) {
#pragma unroll
    for (int q = 0; q < 4; ++q) {
      int row = we * 16 + ch * 4 + q;
      int tgt = p.edge_index[N_EDGES + e0 + row];
      float* ap = p.agg + (size_t)tgt * 64 + r;
#pragma unroll
      for (int t = 0; t < 4; ++t) {
        float oe = (acc[t][q] - mu_[q]) * rs_[q] * gg[t] + tt[t];
        atomicAdd(ap + t * 16, oe * cmb[row * 64 + t * 16 + r]);
      }
    }
  }
}

// ---------------------------------------------------------------------------
struct NodeP {
  const float* agg; const _Float16* x_h; const _Float16* u_h;
  const _Float16* wp; const int* batch;
  const float *Bin, *Bh, *Bout, *G, *Bt;
  float* out;
};

// 64 nodes/block, 256 threads, LDS ~39KB -> 4 blocks/CU, phase-decorrelated.
__global__ __launch_bounds__(256, 4) void node_kernel(NodeP p) {
  __shared__ __align__(16) _Float16 sIn[64 * LDN];
  __shared__ __align__(16) _Float16 sQ[64 * LDH];
  __shared__ int sB[64];
  const int tid = threadIdx.x;
  const int n0 = blockIdx.x * 64;

  if (tid < 64) {
    int n = n0 + tid;
    sB[tid] = (n < N_NODES) ? p.batch[n] : 0;
  }
  __syncthreads();

  for (int idx = tid; idx < 64 * 32; idx += 256) {
    int c = idx & 31, e = idx >> 5;
    if (c >= 21) continue;
    int n = n0 + e, col = c * 8;
    half8 v;
    if (n >= N_NODES || col >= 144) {
#pragma unroll
      for (int j = 0; j < 8; ++j) v[j] = (_Float16)0.f;
    } else if (col < 64) {
      v = *(const half8*)(p.x_h + (size_t)n * 64 + col);
    } else if (col < 128) {
      const float* ag = p.agg + (size_t)n * 64 + (col - 64);
      float4 f0 = *(const float4*)ag, f1 = *(const float4*)(ag + 4);
      v[0] = (_Float16)f0.x; v[1] = (_Float16)f0.y;
      v[2] = (_Float16)f0.z; v[3] = (_Float16)f0.w;
      v[4] = (_Float16)f1.x; v[5] = (_Float16)f1.y;
      v[6] = (_Float16)f1.z; v[7] = (_Float16)f1.w;
    } else {
      v = *(const half8*)(p.u_h + sB[e] * 16 + col - 128);
    }
    *(half8*)(sIn + e * LDN + col) = v;
  }
  __syncthreads();

  const int lane = tid & 63, w = tid >> 6;
  _Float16* sP = sIn;

  gemm32<5, LDN>(sIn, sQ, p.wp + O_NW1, p.Bin, w, lane);      __syncthreads();
  gemm32<4, LDH>(sQ, sP, p.wp + O_NH0, p.Bh, w, lane);        __syncthreads();
  gemm32<4, LDH>(sP, sQ, p.wp + O_NH1, p.Bh + 128, w, lane);  __syncthreads();

  const int r = lane & 15, ch = lane >> 4;
  const half8* wpNo = (const half8*)(p.wp + O_NWO);
  half8 BO[4][4];
#pragma unroll
  for (int s = 0; s < 4; ++s)
#pragma unroll
    for (int t = 0; t < 4; ++t)
      BO[s][t] = wpNo[(s * 4 + ch) * 64 + t * 16 + r];
  f32x4 acc[4];
#pragma unroll
  for (int t = 0; t < 4; ++t) acc[t] = (f32x4){0.f, 0.f, 0.f, 0.f};
#pragma unroll
  for (int s = 0; s < 4; ++s) {
    half8 h = *(const half8*)(sQ + (w * 16 + r) * LDH + s * 32 + ch * 8);
#pragma unroll
    for (int t = 0; t < 4; ++t)
      acc[t] = mfma16(h, BO[s][t], acc[t]);
  }
  float g[4], bt[4];
#pragma unroll
  for (int t = 0; t < 4; ++t) {
    int cidx = t * 16 + r;
    float bov = p.Bout[cidx];
#pragma unroll
    for (int q = 0; q < 4; ++q) acc[t][q] += bov;
    g[t] = p.G[cidx]; bt[t] = p.Bt[cidx];
  }
#pragma unroll
  for (int q = 0; q < 4; ++q) {
    float s1 = 0.f, s2 = 0.f;
#pragma unroll
    for (int t = 0; t < 4; ++t) { float v = acc[t][q]; s1 += v; s2 += v * v; }
#pragma unroll
    for (int mk = 1; mk < 16; mk <<= 1) {
      s1 += __shfl_xor(s1, mk); s2 += __shfl_xor(s2, mk);
    }
    float mu = s1 * (1.f / 64);
    float rs = rsqrtf(s2 * (1.f / 64) - mu * mu + 1e-5f);
    int row = w * 16 + ch * 4 + q;
    int n = n0 + row;
    if (n < N_NODES) {
#pragma unroll
      for (int t = 0; t < 4; ++t)
        p.out[(size_t)n * 64 + t * 16 + r] = (acc[t][q] - mu) * rs * g[t] + bt[t];
    }
  }
}

// ---------------------------------------------------------------------------
// Per-call pack: fp32 weights -> MFMA-B-fragment-packed fp16; x,u -> fp16.
// Packed layout: wdst[((s*4+c)*N + n)*8 + j] = W[s*32+c*8+j][n] (0 if k>=Kreal)
// ---------------------------------------------------------------------------
#define GX 112
struct PackP {
  const float* src[12];
  int Kreal[12], Nlog[12], size[12], dstoff[12];
  const float* x; const float* u;
  _Float16* x_h; _Float16* u_h; _Float16* wdst;
};

__global__ void pack_kernel(PackP p) {
  int y = blockIdx.y;
  int idx = blockIdx.x * 256 + threadIdx.x;
  if (y < 12) {
    int sz = p.size[y];
    if (idx >= sz) return;
    int N = 1 << p.Nlog[y];
    int j = idx & 7, t = idx >> 3;
    int n = t & (N - 1);
    int sc = t >> p.Nlog[y];
    int c = sc & 3, s = sc >> 2;
    int k = s * 32 + c * 8 + j;
    p.wdst[p.dstoff[y] + idx] =
        (k < p.Kreal[y]) ? (_Float16)p.src[y][k * N + n] : (_Float16)0.f;
  } else {
    for (int i = idx; i < N_NODES * 64; i += GX * 256) p.x_h[i] = (_Float16)p.x[i];
    for (int i = idx; i < 64 * 16; i += GX * 256) p.u_h[i] = (_Float16)p.u[i];
  }
}

// ---------------------------------------------------------------------------
extern "C" void kernel_launch(void* const* d_in, const int* in_sizes, int n_in,
                              void* d_out, int out_size, void* d_ws, size_t ws_size,
                              hipStream_t stream) {
  const float* x = (const float*)d_in[0];
  const float* edge_attr = (const float*)d_in[1];
  const float* u = (const float*)d_in[2];
  const int* edge_index = (const int*)d_in[3];
  const int* batch = (const int*)d_in[4];

  char* ws = (char*)d_ws;
  float* agg = (float*)(ws + AGG_OFF);
  _Float16* x_h = (_Float16*)(ws + XH_OFF);
  _Float16* u_h = (_Float16*)(ws + UH_OFF);
  _Float16* wp = (_Float16*)(ws + WP_OFF);

  hipMemsetAsync(agg, 0, (size_t)N_NODES * 64 * sizeof(float), stream);

  PackP pk;
  const float* eWh = (const float*)d_in[7];
  const float* aWh = (const float*)d_in[15];
  const float* nWh = (const float*)d_in[23];
  const float* srcs[12] = {
      (const float*)d_in[5], eWh, eWh + 16384, (const float*)d_in[9],
      (const float*)d_in[13], aWh, aWh + 16384, (const float*)d_in[17],
      (const float*)d_in[21], nWh, nWh + 16384, (const float*)d_in[25]};
  const int kr[12] = {208, 128, 128, 128, 208, 128, 128, 128, 144, 128, 128, 128};
  const int nl[12] = {7, 7, 7, 6, 7, 7, 7, 6, 7, 7, 7, 6};
  const int sz[12] = {28672, 16384, 16384, 8192, 28672, 16384, 16384, 8192,
                      20480, 16384, 16384, 8192};
  const int off[12] = {O_EW1, O_EH0, O_EH1, O_EWO, O_AW1, O_AH0, O_AH1, O_AWO,
                       O_NW1, O_NH0, O_NH1, O_NWO};
  for (int i = 0; i < 12; ++i) {
    pk.src[i] = srcs[i]; pk.Kreal[i] = kr[i]; pk.Nlog[i] = nl[i];
    pk.size[i] = sz[i]; pk.dstoff[i] = off[i];
  }
  pk.x = x; pk.u = u; pk.x_h = x_h; pk.u_h = u_h; pk.wdst = wp;
  pack_kernel<<<dim3(GX, 13), 256, 0, stream>>>(pk);

  EdgeP ep;
  ep.edge_attr = edge_attr; ep.edge_index = edge_index; ep.batch = batch;
  ep.x_h = x_h; ep.u_h = u_h; ep.wp = wp;
  ep.eBin = (const float*)d_in[6];  ep.eBh = (const float*)d_in[8];
  ep.eBout = (const float*)d_in[10]; ep.eG = (const float*)d_in[11];
  ep.eBt = (const float*)d_in[12];
  ep.aBin = (const float*)d_in[14]; ep.aBh = (const float*)d_in[16];
  ep.aBout = (const float*)d_in[18]; ep.aG = (const float*)d_in[19];
  ep.aBt = (const float*)d_in[20];
  ep.agg = agg;
  edge_kernel<<<N_EDGES / 64, 512, 0, stream>>>(ep);

  NodeP np;
  np.agg = agg; np.x_h = x_h; np.u_h = u_h; np.wp = wp; np.batch = batch;
  np.Bin = (const float*)d_in[22]; np.Bh = (const float*)d_in[24];
  np.Bout = (const float*)d_in[26]; np.G = (const float*)d_in[27];
  np.Bt = (const float*)d_in[28];
  np.out = (float*)d_out;
  node_kernel<<<(N_NODES + 63) / 64, 256, 0, stream>>>(np);
}